// Round 5
// baseline (384.951 us; speedup 1.0000x reference)
//
#include <hip/hip_runtime.h>
#include <math.h>

#define HH 160
#define WW 160
#define DD 160
#define VOL (HH*WW*DD)          // 4,096,000
#define KS 11
#define PAD 5
#define NBATCH 2
#define NTOT (NBATCH*VOL)

// fused tile geometry
#define WT 16                    // w outputs per block
#define DT 16                    // d outputs per block
#define HT 32                    // h outputs per block (delay-line walk)
#define WPN (WT + 2*PAD)         // 26 w rows incl. halo
#define NSTEP (HT + 2*PAD)       // 42
// LDS strides (words)
#define RS 68                    // raw row: 32 (s,r) pairs interleaved (+4 pad)
#define P01S 36                  // channel-pair plane row stride
#define P4S 16                   // c4 plane row stride
#define RAW_W (WPN*RS)           // 1768 words per raw buffer
#define P01_W (WPN*P01S)         // 936
#define P4_W  (WPN*P4S)          // 416

typedef float v2f __attribute__((ext_vector_type(2)));
typedef float v4f __attribute__((ext_vector_type(4)));

struct Wts { float w[KS]; };

__device__ __forceinline__ int mirror(int i, int n) {
    if (i < 0) i = -i;
    if (i >= n) i = 2*n - 2 - i;
    return i;
}

// tied VOP3P asm: in-place accumulate, no result-copy movs
__device__ __forceinline__ void pk_fma_acc(v2f& c, v2f a, v2f b) {
    asm("v_pk_fma_f32 %0, %1, %2, %0" : "+v"(c) : "v"(a), "v"(b));
}
__device__ __forceinline__ void pk_add_acc(v2f& c, v2f a) {
    asm("v_pk_add_f32 %0, %0, %1" : "+v"(c) : "v"(a));
}
__device__ __forceinline__ v2f pk_mul(v2f a, v2f b) {
    v2f d; asm("v_pk_mul_f32 %0, %1, %2" : "=v"(d) : "v"(a), "v"(b)); return d;
}

__global__ void init_out(float* out) {
    if (threadIdx.x == 0 && blockIdx.x == 0) out[0] = 1.0f;
}

// Fully fused 3D SSIM.
// Round-4 changes (resubmitted after infra failure): __launch_bounds__(256,4)
// -> VGPR cap 128 (LDS already caps 4 blocks/CU, so free); tied "+v" asm
// removes copy movs; phase1 computes a d-PAIR of points per thread from a
// 12-tap union window (12 b64 reads vs 22, single-shot 208 threads).
__global__ __launch_bounds__(256, 4) void fused(const float* __restrict__ src,
                                                const float* __restrict__ ref,
                                                float* __restrict__ out,
                                                Wts wts, float scale) {
    __shared__ __align__(16) float raw [2*RAW_W];   // (s,r) interleaved window
    __shared__ __align__(16) float pl01[2*P01_W];   // (mu1,mu2)
    __shared__ __align__(16) float pl23[2*P01_W];   // (m11,m22)
    __shared__ __align__(16) float pl4 [2*P4_W];    // m12

    const int bx  = blockIdx.x;
    const int dt_ = bx % (DD/DT);
    const int wt_ = (bx / (DD/DT)) % (WW/WT);
    const int ht_ = (bx / ((DD/DT)*(WW/WT))) % (HH/HT);
    const int b   = bx / ((DD/DT)*(WW/WT)*(HH/HT));
    const int d0 = dt_*DT, w0 = wt_*WT, h0 = ht_*HT;

    // aligned 32-float raw window [dbase, dbase+32) covers all mirrored d-taps
    const int  dbase = (d0 == 0) ? 0 : ((d0 == DD-DT) ? DD-32 : d0-8);
    const bool dedge = (d0 == 0) || (d0 == DD-DT);

    const int tid = threadIdx.x;
    const float* __restrict__ sp = src + (size_t)b*VOL;
    const float* __restrict__ rp = ref + (size_t)b*VOL;

    // ---- stage identity: 208 threads, (row swp, quad sq) ----
    const bool sact = (tid < WPN*8);                 // 208: stage AND phase1
    const int  swp = tid >> 3, sq = tid & 7;
    const int  sgoff  = mirror(w0 - PAD + (sact ? swp : 0), WW)*DD + dbase + sq*4;
    const int  srawof = swp*RS + sq*8;

    // ---- phase1 identity: thread (p_wp, p_dlp) owns points d=2dlp, 2dlp+1 ----
    const int  p_wp  = tid >> 3;                     // 0..25
    const int  p_dlp = tid & 7;                      // 0..7
    const int  pA01  = p_wp*P01S + 4*p_dlp;          // (wp, 2dlp) in c01/c23
    const int  pA4   = p_wp*P4S  + 2*p_dlp;          // (wp, 2dlp) in c4
    // interior-tap base: local tap start = 3 + 2dlp (window math: d0-5+2dlp-dbase=3+2dlp)
    const int  p_rbase = p_wp*RS + 6 + 4*p_dlp;

    // edge-block mirrored d-tap offsets (12-tap union window), hoisted
    int eoff[12];
    if (dedge) {
#pragma unroll
        for (int j = 0; j < 12; ++j)
            eoff[j] = 2*(mirror(d0 + 2*p_dlp - PAD + j, DD) - dbase);
    }

    // ---- phase2 identity: output column (w0+wl, d0+dl2) ----
    const int wl = tid >> 4, dl2 = tid & 15;

    v2f wpk[KS];
#pragma unroll
    for (int k = 0; k < KS; ++k) { wpk[k].x = wts.w[k]; wpk[k].y = wts.w[k]; }

    v2f acc01[KS], acc23[KS];
    float acc4[KS];
#pragma unroll
    for (int s = 0; s < KS; ++s) {
        acc01[s] = (v2f)0.f; acc23[s] = (v2f)0.f; acc4[s] = 0.f;
    }

    // ---- prologue: stage step 0 into raw half 0, prefetch step 1 ----
    v4f ra = (v4f)0.f, rb_ = (v4f)0.f;
    if (sact) {
        const size_t o0 = (size_t)mirror(h0 - PAD, HH)*(WW*DD) + sgoff;
        ra  = *reinterpret_cast<const v4f*>(sp + o0);
        rb_ = *reinterpret_cast<const v4f*>(rp + o0);
        v4f c0, c1;
        c0.x=ra.x; c0.y=rb_.x; c0.z=ra.y; c0.w=rb_.y;
        c1.x=ra.z; c1.y=rb_.z; c1.z=ra.w; c1.w=rb_.w;
        *reinterpret_cast<v4f*>(&raw[srawof])     = c0;
        *reinterpret_cast<v4f*>(&raw[srawof + 4]) = c1;
        const size_t o1 = (size_t)mirror(h0 - PAD + 1, HH)*(WW*DD) + sgoff;
        ra  = *reinterpret_cast<const v4f*>(sp + o1);
        rb_ = *reinterpret_cast<const v4f*>(rp + o1);
    }
    __syncthreads();

    float ssum = 0.f;
    int rawRd = 0, rawWr = RAW_W, po01 = 0, po4 = 0;

    for (int tb = 0; tb < 44; tb += 11) {
#pragma unroll
        for (int ts = 0; ts < 11; ++ts) {
            const int t = tb + ts;
            if (t < NSTEP) {                     // block-uniform
                if (sact) {
                    // ---- A: stage step t+1 (prefetched regs) -> raw[rawWr] ----
                    v4f c0, c1;
                    c0.x=ra.x; c0.y=rb_.x; c0.z=ra.y; c0.w=rb_.y;
                    c1.x=ra.z; c1.y=rb_.z; c1.z=ra.w; c1.w=rb_.w;
                    *reinterpret_cast<v4f*>(&raw[rawWr + srawof])     = c0;
                    *reinterpret_cast<v4f*>(&raw[rawWr + srawof + 4]) = c1;
                    // ---- B: re-issue prefetch for step t+2 (mirror keeps
                    //      overrun addresses in-bounds; data unused) ----
                    const size_t on = (size_t)mirror(h0 - PAD + t + 2, HH)*(WW*DD) + sgoff;
                    ra  = *reinterpret_cast<const v4f*>(sp + on);
                    rb_ = *reinterpret_cast<const v4f*>(rp + on);

                    // ---- C: phase1(t): D-blur for d-pair -> planes ----
                    // point A: taps j=0..10 w[j]; point B: taps j=1..11 w[j-1]
                    v2f muA=(v2f)0.f, mmA=(v2f)0.f, muB=(v2f)0.f, mmB=(v2f)0.f;
                    float m12A=0.f, m12B=0.f;
                    if (!dedge) {
                        const float* r0 = &raw[rawRd + p_rbase];
#pragma unroll
                        for (int j = 0; j < 12; ++j) {
                            v2f sr = *reinterpret_cast<const v2f*>(r0 + 2*j);
                            if (j < 11) {
                                v2f p = pk_mul(sr, wpk[j]);
                                pk_add_acc(muA, p);
                                pk_fma_acc(mmA, p, sr);
                                m12A = fmaf(p.x, sr.y, m12A);
                            }
                            if (j > 0) {
                                v2f p = pk_mul(sr, wpk[j-1]);
                                pk_add_acc(muB, p);
                                pk_fma_acc(mmB, p, sr);
                                m12B = fmaf(p.x, sr.y, m12B);
                            }
                        }
                    } else {
                        const float* r0 = &raw[rawRd + p_wp*RS];
#pragma unroll
                        for (int j = 0; j < 12; ++j) {
                            v2f sr = *reinterpret_cast<const v2f*>(r0 + eoff[j]);
                            if (j < 11) {
                                v2f p = pk_mul(sr, wpk[j]);
                                pk_add_acc(muA, p);
                                pk_fma_acc(mmA, p, sr);
                                m12A = fmaf(p.x, sr.y, m12A);
                            }
                            if (j > 0) {
                                v2f p = pk_mul(sr, wpk[j-1]);
                                pk_add_acc(muB, p);
                                pk_fma_acc(mmB, p, sr);
                                m12B = fmaf(p.x, sr.y, m12B);
                            }
                        }
                    }
                    *reinterpret_cast<v2f*>(&pl01[po01 + pA01])     = muA;
                    *reinterpret_cast<v2f*>(&pl01[po01 + pA01 + 2]) = muB;
                    *reinterpret_cast<v2f*>(&pl23[po01 + pA01])     = mmA;
                    *reinterpret_cast<v2f*>(&pl23[po01 + pA01 + 2]) = mmB;
                    v2f m12w; m12w.x = m12A; m12w.y = m12B;
                    *reinterpret_cast<v2f*>(&pl4[po4 + pA4])        = m12w;
                }

                __syncthreads();                 // the ONLY barrier per step

                // ---- E: phase2(t): W-blur + H-ring + SSIM ----
                {
                    v2f v01 = (v2f)0.f, v23 = (v2f)0.f;
                    float v4v = 0.f;
                    const float* q01 = &pl01[po01 + wl*P01S + 2*dl2];
                    const float* q23 = &pl23[po01 + wl*P01S + 2*dl2];
                    const float* q4  = &pl4 [po4  + wl*P4S  + dl2];
#pragma unroll
                    for (int k = 0; k < KS; ++k) {
                        v2f w = wpk[k];
                        pk_fma_acc(v01, *reinterpret_cast<const v2f*>(q01 + k*P01S), w);
                        pk_fma_acc(v23, *reinterpret_cast<const v2f*>(q23 + k*P01S), w);
                        v4v = fmaf(w.x, q4[k*P4S], v4v);
                    }
#pragma unroll
                    for (int m = 0; m < 11; ++m) {
                        const int slot = (ts + m) % 11;   // static after unroll
                        v2f wt = wpk[10 - m];
                        pk_fma_acc(acc01[slot], v01, wt);
                        pk_fma_acc(acc23[slot], v23, wt);
                        acc4[slot]  = fmaf(wt.x, v4v, acc4[slot]);
                    }
                    if (t >= 10) {                        // emit h = h0 - 10 + t
                        float mu1 = acc01[ts].x, mu2 = acc01[ts].y;
                        float m11 = acc23[ts].x, m22 = acc23[ts].y, m12 = acc4[ts];
                        float mu1sq = mu1*mu1, mu2sq = mu2*mu2, mu12 = mu1*mu2;
                        float s1 = m11 - mu1sq, s2 = m22 - mu2sq, s12 = m12 - mu12;
                        const float C1 = 1e-4f, C2 = 9e-4f;
                        float num = (2.f*mu12 + C1) * (2.f*s12 + C2);
                        float den = (mu1sq + mu2sq + C1) * (s1 + s2 + C2) + 1e-12f;
                        float inv = __builtin_amdgcn_rcpf(den);
                        inv = inv * (2.0f - den * inv);   // 1 NR step -> ~1ulp
                        ssum = fmaf(num, inv, ssum);
                    }
                    acc01[ts] = (v2f)0.f; acc23[ts] = (v2f)0.f; acc4[ts] = 0.f;
                }

                rawRd ^= RAW_W; rawWr ^= RAW_W; po01 ^= P01_W; po4 ^= P4_W;
            }
        }
    }

    // ---- block reduction, one atomic per block ----
#pragma unroll
    for (int off = 32; off > 0; off >>= 1)
        ssum += __shfl_down(ssum, off, 64);
    __shared__ float lsum[4];
    int lane = tid & 63, wid = tid >> 6;
    if (lane == 0) lsum[wid] = ssum;
    __syncthreads();
    if (tid == 0)
        atomicAdd(out, -(lsum[0]+lsum[1]+lsum[2]+lsum[3]) * scale);
}

extern "C" void kernel_launch(void* const* d_in, const int* in_sizes, int n_in,
                              void* d_out, int out_size, void* d_ws, size_t ws_size,
                              hipStream_t stream) {
    const float* src = (const float*)d_in[0];
    const float* ref = (const float*)d_in[1];
    float* out = (float*)d_out;

    Wts wts;
    {
        double g[KS], s = 0.0;
        for (int i = 0; i < KS; ++i) {
            double a = (double)i - (KS - 1) / 2.0;
            g[i] = exp(-(a * a) / (2.0 * 1.5 * 1.5));
            s += g[i];
        }
        for (int i = 0; i < KS; ++i) wts.w[i] = (float)(g[i] / s);
    }

    const float scale = 1.0f / (float)NTOT;

    init_out<<<1, 64, 0, stream>>>(out);
    const int g = NBATCH * (HH/HT) * (WW/WT) * (DD/DT);   // 1000
    fused<<<g, 256, 0, stream>>>(src, ref, out, wts, scale);
}

// Round 6
// 178.927 us; speedup vs baseline: 2.1514x; 2.1514x over previous
//
#include <hip/hip_runtime.h>
#include <math.h>

#define HH 160
#define WW 160
#define DD 160
#define VOL (HH*WW*DD)          // 4,096,000
#define KS 11
#define PAD 5
#define NBATCH 2
#define NTOT (NBATCH*VOL)

// fused tile geometry
#define WT 16                    // w outputs per block
#define DT 16                    // d outputs per block
#define HT 32                    // h outputs per block (delay-line walk)
#define WPN (WT + 2*PAD)         // 26 w rows incl. halo
#define NSTEP (HT + 2*PAD)       // 42
// LDS strides (words) — bank-audited for the wave shapes below
#define RS 74                    // raw row: pair-bank 5wp+2dlp -> max 3-way (was 8-way at 68)
#define P01S 38                  // plane row: pair-bank 19wp+2dlp -> 0 in-wave collisions
#define P4S 16                   // c4 plane row: 16wl+dl2 -> exact 2-way (free)
#define RAW_W (WPN*RS)           // 1924 words per raw buffer
#define P01_W (WPN*P01S)         // 988
#define P4_W  (WPN*P4S)          // 416

typedef float v2f __attribute__((ext_vector_type(2)));
typedef float v4f __attribute__((ext_vector_type(4)));

struct Wts { float w[KS]; };

__device__ __forceinline__ int mirror(int i, int n) {
    if (i < 0) i = -i;
    if (i >= n) i = 2*n - 2 - i;
    return i;
}

// tied VOP3P asm: in-place accumulate, no result-copy movs
__device__ __forceinline__ void pk_fma_acc(v2f& c, v2f a, v2f b) {
    asm("v_pk_fma_f32 %0, %1, %2, %0" : "+v"(c) : "v"(a), "v"(b));
}
__device__ __forceinline__ void pk_add_acc(v2f& c, v2f a) {
    asm("v_pk_add_f32 %0, %0, %1" : "+v"(c) : "v"(a));
}
__device__ __forceinline__ v2f pk_mul(v2f a, v2f b) {
    v2f d; asm("v_pk_mul_f32 %0, %1, %2" : "=v"(d) : "v"(a), "v"(b)); return d;
}

__global__ void init_out(float* out) {
    if (threadIdx.x == 0 && blockIdx.x == 0) out[0] = 1.0f;
}

// Fully fused 3D SSIM.
// Round-6: REVERT launch_bounds min-occupancy (r5: it forced VGPR=64 + 514 MB
// scratch spill). Keep tied "+v" asm + d-pair phase1. Fix the d-pair bank
// conflict: RS 68->74 (8-way -> <=3-way), P01S 36->38 (plane writes 0-conflict).
__global__ __launch_bounds__(256) void fused(const float* __restrict__ src,
                                             const float* __restrict__ ref,
                                             float* __restrict__ out,
                                             Wts wts, float scale) {
    __shared__ __align__(16) float raw [2*RAW_W];   // (s,r) interleaved window
    __shared__ __align__(16) float pl01[2*P01_W];   // (mu1,mu2)
    __shared__ __align__(16) float pl23[2*P01_W];   // (m11,m22)
    __shared__ __align__(16) float pl4 [2*P4_W];    // m12

    const int bx  = blockIdx.x;
    const int dt_ = bx % (DD/DT);
    const int wt_ = (bx / (DD/DT)) % (WW/WT);
    const int ht_ = (bx / ((DD/DT)*(WW/WT))) % (HH/HT);
    const int b   = bx / ((DD/DT)*(WW/WT)*(HH/HT));
    const int d0 = dt_*DT, w0 = wt_*WT, h0 = ht_*HT;

    // aligned 32-float raw window [dbase, dbase+32) covers all mirrored d-taps
    const int  dbase = (d0 == 0) ? 0 : ((d0 == DD-DT) ? DD-32 : d0-8);
    const bool dedge = (d0 == 0) || (d0 == DD-DT);

    const int tid = threadIdx.x;
    const float* __restrict__ sp = src + (size_t)b*VOL;
    const float* __restrict__ rp = ref + (size_t)b*VOL;

    // ---- stage identity: 208 threads, (row swp, quad sq) ----
    const bool sact = (tid < WPN*8);                 // 208: stage AND phase1
    const int  swp = tid >> 3, sq = tid & 7;
    const int  sgoff  = mirror(w0 - PAD + (sact ? swp : 0), WW)*DD + dbase + sq*4;
    const int  srawof = swp*RS + sq*8;

    // ---- phase1 identity: thread (p_wp, p_dlp) owns points d=2dlp, 2dlp+1 ----
    const int  p_wp  = tid >> 3;                     // 0..25
    const int  p_dlp = tid & 7;                      // 0..7
    const int  pA01  = p_wp*P01S + 4*p_dlp;          // (wp, 2dlp) in c01/c23
    const int  pA4   = p_wp*P4S  + 2*p_dlp;          // (wp, 2dlp) in c4
    // interior-tap base: local tap start = 3 + 2dlp -> word 6 + 4dlp
    const int  p_rbase = p_wp*RS + 6 + 4*p_dlp;

    // edge-block mirrored d-tap offsets (12-tap union window), hoisted
    int eoff[12];
    if (dedge) {
#pragma unroll
        for (int j = 0; j < 12; ++j)
            eoff[j] = 2*(mirror(d0 + 2*p_dlp - PAD + j, DD) - dbase);
    }

    // ---- phase2 identity: output column (w0+wl, d0+dl2) ----
    const int wl = tid >> 4, dl2 = tid & 15;

    v2f wpk[KS];
#pragma unroll
    for (int k = 0; k < KS; ++k) { wpk[k].x = wts.w[k]; wpk[k].y = wts.w[k]; }

    v2f acc01[KS], acc23[KS];
    float acc4[KS];
#pragma unroll
    for (int s = 0; s < KS; ++s) {
        acc01[s] = (v2f)0.f; acc23[s] = (v2f)0.f; acc4[s] = 0.f;
    }

    // ---- prologue: stage step 0 into raw half 0, prefetch step 1 ----
    v4f ra = (v4f)0.f, rb_ = (v4f)0.f;
    if (sact) {
        const size_t o0 = (size_t)mirror(h0 - PAD, HH)*(WW*DD) + sgoff;
        ra  = *reinterpret_cast<const v4f*>(sp + o0);
        rb_ = *reinterpret_cast<const v4f*>(rp + o0);
        v2f p0, p1, p2, p3;
        p0.x=ra.x; p0.y=rb_.x;  p1.x=ra.y; p1.y=rb_.y;
        p2.x=ra.z; p2.y=rb_.z;  p3.x=ra.w; p3.y=rb_.w;
        *reinterpret_cast<v2f*>(&raw[srawof])     = p0;
        *reinterpret_cast<v2f*>(&raw[srawof + 2]) = p1;
        *reinterpret_cast<v2f*>(&raw[srawof + 4]) = p2;
        *reinterpret_cast<v2f*>(&raw[srawof + 6]) = p3;
        const size_t o1 = (size_t)mirror(h0 - PAD + 1, HH)*(WW*DD) + sgoff;
        ra  = *reinterpret_cast<const v4f*>(sp + o1);
        rb_ = *reinterpret_cast<const v4f*>(rp + o1);
    }
    __syncthreads();

    float ssum = 0.f;
    int rawRd = 0, rawWr = RAW_W, po01 = 0, po4 = 0;

    for (int tb = 0; tb < 44; tb += 11) {
#pragma unroll
        for (int ts = 0; ts < 11; ++ts) {
            const int t = tb + ts;
            if (t < NSTEP) {                     // block-uniform
                if (sact) {
                    // ---- A: stage step t+1 (prefetched regs) -> raw[rawWr] ----
                    v2f p0, p1, p2, p3;
                    p0.x=ra.x; p0.y=rb_.x;  p1.x=ra.y; p1.y=rb_.y;
                    p2.x=ra.z; p2.y=rb_.z;  p3.x=ra.w; p3.y=rb_.w;
                    *reinterpret_cast<v2f*>(&raw[rawWr + srawof])     = p0;
                    *reinterpret_cast<v2f*>(&raw[rawWr + srawof + 2]) = p1;
                    *reinterpret_cast<v2f*>(&raw[rawWr + srawof + 4]) = p2;
                    *reinterpret_cast<v2f*>(&raw[rawWr + srawof + 6]) = p3;
                    // ---- B: re-issue prefetch for step t+2 (mirror keeps
                    //      overrun addresses in-bounds; data unused) ----
                    const size_t on = (size_t)mirror(h0 - PAD + t + 2, HH)*(WW*DD) + sgoff;
                    ra  = *reinterpret_cast<const v4f*>(sp + on);
                    rb_ = *reinterpret_cast<const v4f*>(rp + on);

                    // ---- C: phase1(t): D-blur for d-pair -> planes ----
                    // point A: taps j=0..10 w[j]; point B: taps j=1..11 w[j-1]
                    v2f muA=(v2f)0.f, mmA=(v2f)0.f, muB=(v2f)0.f, mmB=(v2f)0.f;
                    float m12A=0.f, m12B=0.f;
                    if (!dedge) {
                        const float* r0 = &raw[rawRd + p_rbase];
#pragma unroll
                        for (int j = 0; j < 12; ++j) {
                            v2f sr = *reinterpret_cast<const v2f*>(r0 + 2*j);
                            if (j < 11) {
                                v2f p = pk_mul(sr, wpk[j]);
                                pk_add_acc(muA, p);
                                pk_fma_acc(mmA, p, sr);
                                m12A = fmaf(p.x, sr.y, m12A);
                            }
                            if (j > 0) {
                                v2f p = pk_mul(sr, wpk[j-1]);
                                pk_add_acc(muB, p);
                                pk_fma_acc(mmB, p, sr);
                                m12B = fmaf(p.x, sr.y, m12B);
                            }
                        }
                    } else {
                        const float* r0 = &raw[rawRd + p_wp*RS];
#pragma unroll
                        for (int j = 0; j < 12; ++j) {
                            v2f sr = *reinterpret_cast<const v2f*>(r0 + eoff[j]);
                            if (j < 11) {
                                v2f p = pk_mul(sr, wpk[j]);
                                pk_add_acc(muA, p);
                                pk_fma_acc(mmA, p, sr);
                                m12A = fmaf(p.x, sr.y, m12A);
                            }
                            if (j > 0) {
                                v2f p = pk_mul(sr, wpk[j-1]);
                                pk_add_acc(muB, p);
                                pk_fma_acc(mmB, p, sr);
                                m12B = fmaf(p.x, sr.y, m12B);
                            }
                        }
                    }
                    *reinterpret_cast<v2f*>(&pl01[po01 + pA01])     = muA;
                    *reinterpret_cast<v2f*>(&pl01[po01 + pA01 + 2]) = muB;
                    *reinterpret_cast<v2f*>(&pl23[po01 + pA01])     = mmA;
                    *reinterpret_cast<v2f*>(&pl23[po01 + pA01 + 2]) = mmB;
                    v2f m12w; m12w.x = m12A; m12w.y = m12B;
                    *reinterpret_cast<v2f*>(&pl4[po4 + pA4])        = m12w;
                }

                __syncthreads();                 // the ONLY barrier per step

                // ---- E: phase2(t): W-blur + H-ring + SSIM ----
                {
                    v2f v01 = (v2f)0.f, v23 = (v2f)0.f;
                    float v4v = 0.f;
                    const float* q01 = &pl01[po01 + wl*P01S + 2*dl2];
                    const float* q23 = &pl23[po01 + wl*P01S + 2*dl2];
                    const float* q4  = &pl4 [po4  + wl*P4S  + dl2];
#pragma unroll
                    for (int k = 0; k < KS; ++k) {
                        v2f w = wpk[k];
                        pk_fma_acc(v01, *reinterpret_cast<const v2f*>(q01 + k*P01S), w);
                        pk_fma_acc(v23, *reinterpret_cast<const v2f*>(q23 + k*P01S), w);
                        v4v = fmaf(w.x, q4[k*P4S], v4v);
                    }
#pragma unroll
                    for (int m = 0; m < 11; ++m) {
                        const int slot = (ts + m) % 11;   // static after unroll
                        v2f wt = wpk[10 - m];
                        pk_fma_acc(acc01[slot], v01, wt);
                        pk_fma_acc(acc23[slot], v23, wt);
                        acc4[slot]  = fmaf(wt.x, v4v, acc4[slot]);
                    }
                    if (t >= 10) {                        // emit h = h0 - 10 + t
                        float mu1 = acc01[ts].x, mu2 = acc01[ts].y;
                        float m11 = acc23[ts].x, m22 = acc23[ts].y, m12 = acc4[ts];
                        float mu1sq = mu1*mu1, mu2sq = mu2*mu2, mu12 = mu1*mu2;
                        float s1 = m11 - mu1sq, s2 = m22 - mu2sq, s12 = m12 - mu12;
                        const float C1 = 1e-4f, C2 = 9e-4f;
                        float num = (2.f*mu12 + C1) * (2.f*s12 + C2);
                        float den = (mu1sq + mu2sq + C1) * (s1 + s2 + C2) + 1e-12f;
                        float inv = __builtin_amdgcn_rcpf(den);
                        inv = inv * (2.0f - den * inv);   // 1 NR step -> ~1ulp
                        ssum = fmaf(num, inv, ssum);
                    }
                    acc01[ts] = (v2f)0.f; acc23[ts] = (v2f)0.f; acc4[ts] = 0.f;
                }

                rawRd ^= RAW_W; rawWr ^= RAW_W; po01 ^= P01_W; po4 ^= P4_W;
            }
        }
    }

    // ---- block reduction, one atomic per block ----
#pragma unroll
    for (int off = 32; off > 0; off >>= 1)
        ssum += __shfl_down(ssum, off, 64);
    __shared__ float lsum[4];
    int lane = tid & 63, wid = tid >> 6;
    if (lane == 0) lsum[wid] = ssum;
    __syncthreads();
    if (tid == 0)
        atomicAdd(out, -(lsum[0]+lsum[1]+lsum[2]+lsum[3]) * scale);
}

extern "C" void kernel_launch(void* const* d_in, const int* in_sizes, int n_in,
                              void* d_out, int out_size, void* d_ws, size_t ws_size,
                              hipStream_t stream) {
    const float* src = (const float*)d_in[0];
    const float* ref = (const float*)d_in[1];
    float* out = (float*)d_out;

    Wts wts;
    {
        double g[KS], s = 0.0;
        for (int i = 0; i < KS; ++i) {
            double a = (double)i - (KS - 1) / 2.0;
            g[i] = exp(-(a * a) / (2.0 * 1.5 * 1.5));
            s += g[i];
        }
        for (int i = 0; i < KS; ++i) wts.w[i] = (float)(g[i] / s);
    }

    const float scale = 1.0f / (float)NTOT;

    init_out<<<1, 64, 0, stream>>>(out);
    const int g = NBATCH * (HH/HT) * (WW/WT) * (DD/DT);   // 1000
    fused<<<g, 256, 0, stream>>>(src, ref, out, wts, scale);
}